// Round 1
// baseline (576.506 us; speedup 1.0000x reference)
//
#include <hip/hip_runtime.h>

#define N_VOX 262144
#define C 64          // C_IN == C_OUT == 64
#define K_VOL 27
#define P_PER_OFF 65536

#define WAVES_PER_BLOCK 4
#define BLOCK (WAVES_PER_BLOCK * 64)
#define PAIRS_PER_WAVE 256
#define BLOCKS_PER_K (P_PER_OFF / (PAIRS_PER_WAVE * WAVES_PER_BLOCK))  // 64

typedef __attribute__((ext_vector_type(16))) float f32x16;

// Each wave owns one column-slice of W[k] in VGPRs (w[i] = W[k][i][lane]) and
// streams pairs: feat row -> SGPRs (wave-uniform scalar loads), 64 FMAs with
// SGPR broadcast operand, then one f32 atomic per lane into out[tgt].
__global__ __launch_bounds__(BLOCK) void conv_scatter(
    const float* __restrict__ feat,
    const float* __restrict__ kern,
    const int* __restrict__ src_ids,
    const int* __restrict__ tgt_ids,
    float* __restrict__ out)
{
    const int k    = blockIdx.y;
    const int wave = threadIdx.x >> 6;
    const int lane = threadIdx.x & 63;
    const int pbase = (blockIdx.x * WAVES_PER_BLOCK + wave) * PAIRS_PER_WAVE;

    // W[k] column `lane`: 64 VGPRs, coalesced loads (lane-contiguous), reused
    // over all PAIRS_PER_WAVE pairs.
    float w[C];
    #pragma unroll
    for (int i = 0; i < C; ++i)
        w[i] = kern[(size_t)k * C * C + (size_t)i * C + lane];

    const int* sp = src_ids + (size_t)k * P_PER_OFF + pbase;
    const int* tp = tgt_ids + (size_t)k * P_PER_OFF + pbase;

    for (int j0 = 0; j0 < PAIRS_PER_WAVE; j0 += 64) {
        // batch-load 64 pairs' ids, lane-spread (coalesced)
        int sv = sp[j0 + lane];
        int tv = tp[j0 + lane];

        #pragma unroll 2
        for (int j = 0; j < 64; ++j) {
            int usrc = __builtin_amdgcn_readlane(sv, j);   // wave-uniform
            int utgt = __builtin_amdgcn_readlane(tv, j);

            const float* frow = feat + (size_t)usrc * C;

            // Full 64-float feat row into SGPRs. Outputs early-clobber so the
            // destination tuples can't alias the base-address pair; the
            // waitcnt lives in the same asm so every consumer has a data dep.
            f32x16 fa, fb, fc, fd;
            asm volatile(
                "s_load_dwordx16 %0, %4, 0x0\n\t"
                "s_load_dwordx16 %1, %4, 0x40\n\t"
                "s_load_dwordx16 %2, %4, 0x80\n\t"
                "s_load_dwordx16 %3, %4, 0xc0\n\t"
                "s_waitcnt lgkmcnt(0)"
                : "=&s"(fa), "=&s"(fb), "=&s"(fc), "=&s"(fd)
                : "s"(frow));

            // 64 FMAs, 4 independent accumulator chains (16 deps each)
            float a0 = 0.f, a1 = 0.f, a2 = 0.f, a3 = 0.f;
            #pragma unroll
            for (int i = 0; i < 16; ++i) {
                a0 = fmaf(fa[i], w[i],      a0);
                a1 = fmaf(fb[i], w[16 + i], a1);
                a2 = fmaf(fc[i], w[32 + i], a2);
                a3 = fmaf(fd[i], w[48 + i], a3);
            }
            float r = (a0 + a1) + (a2 + a3);

            // native global_atomic_add_f32 (avoid CAS-loop lowering)
            unsafeAtomicAdd(out + (size_t)utgt * C + lane, r);
        }
    }
}

extern "C" void kernel_launch(void* const* d_in, const int* in_sizes, int n_in,
                              void* d_out, int out_size, void* d_ws, size_t ws_size,
                              hipStream_t stream)
{
    const float* feat = (const float*)d_in[0];
    const float* kern = (const float*)d_in[1];
    const int*   src  = (const int*)d_in[2];
    const int*   tgt  = (const int*)d_in[3];
    float* out = (float*)d_out;

    // harness poisons d_out with 0xAA before every launch
    hipMemsetAsync(out, 0, (size_t)N_VOX * C * sizeof(float), stream);

    dim3 grid(BLOCKS_PER_K, K_VOL);
    conv_scatter<<<grid, BLOCK, 0, stream>>>(feat, kern, src, tgt, out);
}

// Round 3
// 470.713 us; speedup vs baseline: 1.2248x; 1.2248x over previous
//
#include <hip/hip_runtime.h>

#define N_VOX 262144
#define C 64          // C_IN == C_OUT
#define K_VOL 27
#define P 65536

#define BLOCK 256
#define WAVES 4
#define PAIRS_PER_WAVE 256            // 16 batches x 16 pairs
#define NBATCH 16
#define BLOCKS_PER_K (P / (PAIRS_PER_WAVE * WAVES))   // 64

typedef __attribute__((ext_vector_type(8))) short bf16x8;   // 8 bf16 in 4 VGPRs
typedef __attribute__((ext_vector_type(4))) float f32x4;

__device__ inline unsigned short cvt_bf16_rne(float x) {
    unsigned u = __builtin_bit_cast(unsigned, x);
    u += 0x7fff + ((u >> 16) & 1);          // round-to-nearest-even
    return (unsigned short)(u >> 16);
}
__device__ inline float bf16f(unsigned short h) {
    unsigned u = (unsigned)h << 16;
    return __builtin_bit_cast(float, u);
}

// Per k-offset GEMM out[tgt] += feat[src] @ W[k] via 16x16x32 bf16 MFMA,
// fp32 emulated with 3-pass hi/lo split. W[k] lives in VGPRs as bf16 hi/lo.
__global__ __launch_bounds__(BLOCK) void conv_mfma(
    const float* __restrict__ feat,
    const float* __restrict__ kern,
    const int* __restrict__ src_ids,
    const int* __restrict__ tgt_ids,
    float* __restrict__ out)
{
    const int k    = blockIdx.y;
    const int wave = threadIdx.x >> 6;
    const int lane = threadIdx.x & 63;
    const int g    = lane >> 4;      // operand k-group 0..3
    const int col  = lane & 15;      // A-row / B-col / C-col selector

    // ---- W_k -> register fragments, bf16 hi/lo (loaded once, reused 256 pairs)
    // B layout: lane holds B[k = kt*32 + g*8 + i][n = nt*16 + col]
    bf16x8 Bhi[2][4], Blo[2][4];
    {
        const float* Wk = kern + (size_t)k * C * C;
        #pragma unroll
        for (int kt = 0; kt < 2; ++kt)
            #pragma unroll
            for (int nt = 0; nt < 4; ++nt)
                #pragma unroll
                for (int i = 0; i < 8; ++i) {
                    float w = Wk[(size_t)(kt * 32 + g * 8 + i) * C + nt * 16 + col];
                    unsigned short h = cvt_bf16_rne(w);
                    Bhi[kt][nt][i] = (short)h;
                    Blo[kt][nt][i] = (short)cvt_bf16_rne(w - bf16f(h));
                }
    }

    const int pb0 = (blockIdx.x * WAVES + wave) * PAIRS_PER_WAVE;
    const int* srcp = src_ids + (size_t)k * P + pb0;
    const int* tgtp = tgt_ids + (size_t)k * P + pb0;

    // ---- software pipeline: ids dist-2, A-rows & tgt dist-1 ----
    f32x4 ra0, ra1, ra2, ra3;            // raw f32 feat chunk, current batch
    int tg0, tg1, tg2, tg3;              // tgt ids, current batch

    int sv = srcp[col];                  // batch 0 src (A-row = col)
    {
        const float* fr = feat + (size_t)sv * C + g * 8;
        ra0 = *(const f32x4*)(fr);       // kt0, i 0..3
        ra1 = *(const f32x4*)(fr + 4);   // kt0, i 4..7
        ra2 = *(const f32x4*)(fr + 32);  // kt1, i 0..3
        ra3 = *(const f32x4*)(fr + 36);  // kt1, i 4..7
    }
    int sv_n = srcp[16 + col];           // batch 1 src, pending
    tg0 = tgtp[g * 4 + 0];
    tg1 = tgtp[g * 4 + 1];
    tg2 = tgtp[g * 4 + 2];
    tg3 = tgtp[g * 4 + 3];

    for (int b = 0; b < NBATCH; ++b) {
        // convert current A batch to bf16 hi/lo frags (consumes ra*)
        bf16x8 Ahi[2], Alo[2];
        #pragma unroll
        for (int i = 0; i < 4; ++i) {
            float x0 = ra0[i], x1 = ra1[i], x2 = ra2[i], x3 = ra3[i];
            unsigned short h;
            h = cvt_bf16_rne(x0); Ahi[0][i]     = (short)h; Alo[0][i]     = (short)cvt_bf16_rne(x0 - bf16f(h));
            h = cvt_bf16_rne(x1); Ahi[0][4 + i] = (short)h; Alo[0][4 + i] = (short)cvt_bf16_rne(x1 - bf16f(h));
            h = cvt_bf16_rne(x2); Ahi[1][i]     = (short)h; Alo[1][i]     = (short)cvt_bf16_rne(x2 - bf16f(h));
            h = cvt_bf16_rne(x3); Ahi[1][4 + i] = (short)h; Alo[1][4 + i] = (short)cvt_bf16_rne(x3 - bf16f(h));
        }

        // stash current tgts, prefetch next batch's (keeps atomic waits off the
        // critical path: tg is older than this iter's atomics when consumed)
        const int ctg0 = tg0, ctg1 = tg1, ctg2 = tg2, ctg3 = tg3;
        if (b + 1 < NBATCH) {
            const int* tp = tgtp + (b + 1) * 16 + g * 4;
            tg0 = tp[0]; tg1 = tp[1]; tg2 = tp[2]; tg3 = tp[3];
        }

        // issue next batch's gather (sv_n was loaded an iteration ago)
        if (b + 1 < NBATCH) {
            const float* fr = feat + (size_t)sv_n * C + g * 8;
            ra0 = *(const f32x4*)(fr);
            ra1 = *(const f32x4*)(fr + 4);
            ra2 = *(const f32x4*)(fr + 32);
            ra3 = *(const f32x4*)(fr + 36);
            if (b + 2 < NBATCH) sv_n = srcp[(b + 2) * 16 + col];
        }

        // 24 MFMAs: 4 n-tiles x 2 k-tiles x {hi*hi, lo*hi, hi*lo}
        f32x4 acc[4] = {f32x4{0.f,0.f,0.f,0.f}, f32x4{0.f,0.f,0.f,0.f},
                        f32x4{0.f,0.f,0.f,0.f}, f32x4{0.f,0.f,0.f,0.f}};
        #pragma unroll
        for (int kt = 0; kt < 2; ++kt) {
            #pragma unroll
            for (int nt = 0; nt < 4; ++nt)
                acc[nt] = __builtin_amdgcn_mfma_f32_16x16x32_bf16(Ahi[kt], Bhi[kt][nt], acc[nt], 0, 0, 0);
            #pragma unroll
            for (int nt = 0; nt < 4; ++nt)
                acc[nt] = __builtin_amdgcn_mfma_f32_16x16x32_bf16(Alo[kt], Bhi[kt][nt], acc[nt], 0, 0, 0);
            #pragma unroll
            for (int nt = 0; nt < 4; ++nt)
                acc[nt] = __builtin_amdgcn_mfma_f32_16x16x32_bf16(Ahi[kt], Blo[kt][nt], acc[nt], 0, 0, 0);
        }

        // scatter: C/D layout row=g*4+r, col=nt*16+col -> coalesced row atomics
        float* o0 = out + (size_t)ctg0 * C + col;
        float* o1 = out + (size_t)ctg1 * C + col;
        float* o2 = out + (size_t)ctg2 * C + col;
        float* o3 = out + (size_t)ctg3 * C + col;
        #pragma unroll
        for (int nt = 0; nt < 4; ++nt) {
            unsafeAtomicAdd(o0 + nt * 16, acc[nt][0]);
            unsafeAtomicAdd(o1 + nt * 16, acc[nt][1]);
            unsafeAtomicAdd(o2 + nt * 16, acc[nt][2]);
            unsafeAtomicAdd(o3 + nt * 16, acc[nt][3]);
        }
    }
}

extern "C" void kernel_launch(void* const* d_in, const int* in_sizes, int n_in,
                              void* d_out, int out_size, void* d_ws, size_t ws_size,
                              hipStream_t stream)
{
    const float* feat = (const float*)d_in[0];
    const float* kern = (const float*)d_in[1];
    const int*   src  = (const int*)d_in[2];
    const int*   tgt  = (const int*)d_in[3];
    float* out = (float*)d_out;

    // harness poisons d_out with 0xAA before every launch
    hipMemsetAsync(out, 0, (size_t)N_VOX * C * sizeof(float), stream);

    dim3 grid(BLOCKS_PER_K, K_VOL);
    conv_mfma<<<grid, BLOCK, 0, stream>>>(feat, kern, src, tgt, out);
}